// Round 6
// baseline (723.621 us; speedup 1.0000x reference)
//
#include <hip/hip_runtime.h>
#include <math.h>

typedef _Float16 f16;
typedef _Float16 half8 __attribute__((ext_vector_type(8)));
typedef float floatx4 __attribute__((ext_vector_type(4)));

// ---------------- ws layout (bytes) ---- PROVEN EXTENT ONLY, R2-identical ---
// [0, 94208)       f16 HI weights, padded+transposed+bank-swizzled (R2 k0, verbatim)
//   L0: [64][32]  @0      L1: [112][64] @2048   L2: [112][128] @9216
//   L3: [112][128]@23552  L4: [64][128] @37888  L5: [16][64]   @46080
// [94208, 96128)   f32 biases, zero-padded to Np per layer (480 floats)
// NOTHING beyond 96128 is touched (rounds 2/5 evidence: that region is unsafe).
// LO residual weights are derived on the fly from the f32 inputs (d_in).

// Lo-plane scale: residuals (~2^-11 of value) are stored as f16 scaled by 2^8
// to stay in f16-normal range; accumulated in a separate MFMA accumulator C2
// and recombined as C1 + C2 * (1/256) in f32.
#define LO_SCALE 256.0f
#define LO_INV   (1.0f/256.0f)

__device__ __forceinline__ void mm3(const float* A, const float* Bm, float* C) {
  #pragma unroll
  for (int i = 0; i < 3; ++i)
    #pragma unroll
    for (int j = 0; j < 3; ++j)
      C[i*3+j] = A[i*3]*Bm[j] + A[i*3+1]*Bm[3+j] + A[i*3+2]*Bm[6+j];
}

// ---------------- k0: weight/bias prep (R2-passing version, VERBATIM) -------
__global__ void k0_prep(const float* W0, const float* B0, const float* W1, const float* B1,
                        const float* W2, const float* B2, const float* W3, const float* B3,
                        const float* W4, const float* B4, const float* W5, const float* B5,
                        f16* wt, float* biasp) {
  int idx = blockIdx.x * 256 + threadIdx.x;
  if (idx < 47104) {
    const float* W; int K, N, sh, loc;
    if (idx < 2048)       { W = W0; K = 5;   N = 50;  sh = 5; loc = idx; }
    else if (idx < 9216)  { W = W1; K = 50;  N = 100; sh = 6; loc = idx - 2048; }
    else if (idx < 23552) { W = W2; K = 100; N = 100; sh = 7; loc = idx - 9216; }
    else if (idx < 37888) { W = W3; K = 100; N = 100; sh = 7; loc = idx - 23552; }
    else if (idx < 46080) { W = W4; K = 100; N = 50;  sh = 7; loc = idx - 37888; }
    else                  { W = W5; K = 50;  N = 10;  sh = 6; loc = idx - 46080; }
    int Kp  = 1 << sh;
    int n   = loc >> sh;
    int kp  = loc & (Kp - 1);
    int chm = (Kp >> 3) - 1;                                   // chunk swizzle mask
    int klog = (((kp >> 3) ^ (n & chm)) << 3) | (kp & 7);      // XOR swizzle (involution)
    float v = (n < N && klog < K) ? W[klog * N + n] : 0.f;     // transpose: Wt[n][k] = W[k][n]
    wt[idx] = (f16)v;
  }
  int bi = idx - 47104;
  if (bi >= 0 && bi < 480) {
    const float* Bv; int N, loc;
    if (bi < 64)       { Bv = B0; N = 50;  loc = bi; }
    else if (bi < 176) { Bv = B1; N = 100; loc = bi - 64; }
    else if (bi < 288) { Bv = B2; N = 100; loc = bi - 176; }
    else if (bi < 400) { Bv = B3; N = 100; loc = bi - 288; }
    else if (bi < 464) { Bv = B4; N = 50;  loc = bi - 400; }
    else               { Bv = B5; N = 10;  loc = bi - 464; }
    biasp[bi] = (loc < N) ? Bv[loc] : 0.f;
  }
}

// ---------------- MLP layer: split-f16 GEMM, lo derived from f32 inputs ----
// Block = 256 thr = 4 waves, 64 batch rows/block. Transposed GEMM: y^T = Wt @ x^T
//   A-frag hi (Wt): row n = nt*16 + (lane&15), logical k = (kt*4+q)*8 + j,
//                   read from proven ws bytes (same as passing R3/R4 rounds).
//   A-frag lo:      residual vs the f32 input weight Wf[k*ND+n], scaled 2^8,
//                   computed in-register (no ws beyond 96128 touched).
//   B-frag (x):     hi/lo LDS buffers, swizzle chunk' = chunk ^ (row & 15).
//   Accumulate:     C1 += Ah*Bh ;  C2 += Ah*Bl' + Al'*Bh  (primed = 2^8-scaled)
//   Recombine:      y = C1 + C2/256 (+bias), exact to ~2^-22 relative.
// One __syncthreads per layer (proven race-free in R3/R4 runs).
template<int KP, int NP, int KD, int ND, int WOFF, int BOFF, int LIDX>
__device__ __forceinline__ void mlp_layer(
    const f16* __restrict__ wt, const float* __restrict__ biasp,
    const float* __restrict__ Wf,
    const f16* linv_h, const f16* linv_l, float* gLDS,
    const f16* xsh, const f16* xsl, f16* ydh, f16* ydl, int tid) {
  const int lane = tid & 63;
  const int wv   = tid >> 6;
  const int mh   = lane & 15;
  const int q    = lane >> 4;

  constexpr int NT = NP / 16;
  constexpr int KT = KP / 32;
  int nt0, ntc;
  if constexpr (NT == 7)      { nt0 = wv; ntc = (wv < 3) ? 2 : 1; }  // tiles {wv, wv+4}
  else if constexpr (NT == 4) { nt0 = wv; ntc = 1; }
  else                        { nt0 = 0;  ntc = (wv == 0) ? 1 : 0; } // NT==1 (final)

  // A-frags: hi from proven ws; lo = scaled residual vs pristine f32 weights.
  half8 Ah[2][KT], Al[2][KT];
  #pragma unroll
  for (int i = 0; i < 2; ++i)
    #pragma unroll
    for (int kt = 0; kt < KT; ++kt) {
      Ah[i][kt] = (half8)(f16)0.f;
      Al[i][kt] = (half8)(f16)0.f;
      if (i < ntc) {
        int n   = (nt0 + i*4) * 16 + mh;
        int cph = (kt*4 + q) ^ (n & ((KP >> 3) - 1));
        Ah[i][kt] = *(const half8*)(wt + WOFF + n*KP + cph*8);
        int kbase = (kt*4 + q) * 8;                 // logical k of element j=0
        half8 al;
        #pragma unroll
        for (int j = 0; j < 8; ++j) {
          int k = kbase + j;
          float v = (n < ND && k < KD) ? Wf[k*ND + n] : 0.f;
          al[j] = (f16)((v - (float)Ah[i][kt][j]) * LO_SCALE);
        }
        Al[i][kt] = al;
      }
    }

  __syncthreads();   // prev layer's LDS writes visible; its reads of our ydst done

  floatx4 C1[2][4], C2[2][4];
  #pragma unroll
  for (int i = 0; i < 2; ++i)
    #pragma unroll
    for (int r = 0; r < 4; ++r) {
      C1[i][r] = (floatx4){0.f, 0.f, 0.f, 0.f};
      C2[i][r] = (floatx4){0.f, 0.f, 0.f, 0.f};
    }

  #pragma unroll
  for (int kt = 0; kt < KT; ++kt) {
    half8 Bh[4], Bl[4];
    #pragma unroll
    for (int r = 0; r < 4; ++r) {
      if constexpr (LIDX == 0) {
        half8 zh = {(f16)0.f,(f16)0.f,(f16)0.f,(f16)0.f,(f16)0.f,(f16)0.f,(f16)0.f,(f16)0.f};
        half8 zl = zh;
        if (q == 0) {
          zh = *(const half8*)(linv_h + (r*16 + mh)*8);
          zl = *(const half8*)(linv_l + (r*16 + mh)*8);
        }
        Bh[r] = zh; Bl[r] = zl;                      // K=5 padded to 32: quads 1-3 zero
      } else {
        int row = r*16 + mh;
        int cph = (kt*4 + q) ^ mh;
        Bh[r] = *(const half8*)(xsh + row*128 + cph*8);
        Bl[r] = *(const half8*)(xsl + row*128 + cph*8);
      }
    }
    #pragma unroll
    for (int i = 0; i < 2; ++i) {
      if (i < ntc) {
        #pragma unroll
        for (int r = 0; r < 4; ++r) {
          C1[i][r] = __builtin_amdgcn_mfma_f32_16x16x32_f16(Ah[i][kt], Bh[r], C1[i][r], 0, 0, 0);
          C2[i][r] = __builtin_amdgcn_mfma_f32_16x16x32_f16(Ah[i][kt], Bl[r], C2[i][r], 0, 0, 0);
          C2[i][r] = __builtin_amdgcn_mfma_f32_16x16x32_f16(Al[i][kt], Bh[r], C2[i][r], 0, 0, 0);
        }
      }
    }
  }

  #pragma unroll
  for (int i = 0; i < 2; ++i) {
    if (i < ntc) {
      int nt = nt0 + i*4;
      if constexpr (LIDX < 5) {
        floatx4 bia = *(const floatx4*)(biasp + BOFF + nt*16 + q*4);
        #pragma unroll
        for (int r = 0; r < 4; ++r) {
          union { f16 h[4]; uint2 u; } pkh, pkl;
          #pragma unroll
          for (int e = 0; e < 4; ++e) {
            float v = C1[i][r][e] + C2[i][r][e] * LO_INV + bia[e];
            v = (v > 0.f) ? v : 0.1f * v;            // leaky_relu(0.1) in f32
            f16 h = (f16)v;
            pkh.h[e] = h;
            pkl.h[e] = (f16)((v - (float)h) * LO_SCALE);   // scaled residual
          }
          int row = r*16 + mh;                        // batch row (lane&15)
          int cph = (nt*2 + (q >> 1)) ^ mh;           // swizzled chunk of col nt*16+q*4
          *(uint2*)(ydh + row*128 + cph*8 + (q & 1)*4) = pkh.u;
          *(uint2*)(ydl + row*128 + cph*8 + (q & 1)*4) = pkl.u;
        }
      } else {
        floatx4 bia = *(const floatx4*)(biasp + BOFF + q*4);
        #pragma unroll
        for (int r = 0; r < 4; ++r) {
          int slot = r*16 + mh;
          #pragma unroll
          for (int e = 0; e < 4; ++e) {
            int n = q*4 + e;
            if (n < 10) gLDS[slot*10 + n] = C1[i][r][e] + C2[i][r][e] * LO_INV + bia[e];
          }
        }
      }
    }
  }
}

// ---------------- fused kernel: invariants -> split-f16 MLP -> bases --------
__global__ __launch_bounds__(256, 2) void k_fused(
    const f16* __restrict__ wt, const float* __restrict__ biasp,
    const float* __restrict__ W0f, const float* __restrict__ W1f,
    const float* __restrict__ W2f, const float* __restrict__ W3f,
    const float* __restrict__ W4f, const float* __restrict__ W5f,
    const float* __restrict__ s, const float* __restrict__ w,
    float* __restrict__ out, int B) {
  __shared__ __align__(16) f16 lds_xh[2][64*128];    // 2 x 16384 B hi ping-pong
  __shared__ __align__(16) f16 lds_xl[2][64*128];    // 2 x 16384 B lo ping-pong
  __shared__ __align__(16) f16 linv_h[64*8];         // 1024 B invariants hi
  __shared__ __align__(16) f16 linv_l[64*8];         // 1024 B invariants lo (scaled)
  __shared__ __align__(16) float gLDS[64*10];        // 2560 B g (f32)
  int tid = threadIdx.x;
  int blockRow = blockIdx.x * 64;

  // zero all activation buffers (padding chunks must be exact zero)
  {
    int4 z; z.x = 0; z.y = 0; z.z = 0; z.w = 0;
    int4* ph = (int4*)&lds_xh[0][0];
    int4* pl = (int4*)&lds_xl[0][0];
    #pragma unroll 1
    for (int i = tid; i < 2048; i += 256) { ph[i] = z; pl[i] = z; }
  }

  // ---- phase A: invariants (f32, split to f16 hi + scaled lo) ----
  if (tid < 64) {
    int row = blockRow + tid;
    union { f16 h[8]; int4 v; } uh, ul;
    uh.v.x = 0; uh.v.y = 0; uh.v.z = 0; uh.v.w = 0;
    ul.v = uh.v;
    if (row < B) {
      float S[9], W[9];
      #pragma unroll
      for (int i = 0; i < 9; ++i) { S[i] = s[(size_t)row*9 + i]; W[i] = w[(size_t)row*9 + i]; }
      float S2[9], W2[9];
      mm3(S, S, S2); mm3(W, W, W2);
      float lam[5];
      lam[0] = S2[0] + S2[4] + S2[8];
      lam[1] = W2[0] + W2[4] + W2[8];
      lam[2] = 0.f; lam[3] = 0.f; lam[4] = 0.f;
      #pragma unroll
      for (int i = 0; i < 3; ++i)
        #pragma unroll
        for (int j = 0; j < 3; ++j) {
          float sji = S[j*3 + i];
          lam[2] += S2[i*3 + j] * sji;
          lam[3] += W2[i*3 + j] * sji;
          lam[4] += W2[i*3 + j] * S2[j*3 + i];
        }
      #pragma unroll
      for (int i = 0; i < 5; ++i) {
        f16 h = (f16)lam[i];
        uh.h[i] = h;
        ul.h[i] = (f16)((lam[i] - (float)h) * LO_SCALE);
      }
    }
    *(int4*)(linv_h + tid*8) = uh.v;
    *(int4*)(linv_l + tid*8) = ul.v;
  }
  // ordering: phase A / zero-init precede layer 0's internal __syncthreads

  // ---- phase B: 6 split-f16 MFMA layers ----
  mlp_layer< 32,  64,   5,  50,     0,   0, 0>(wt, biasp, W0f, linv_h, linv_l, gLDS,
      (const f16*)nullptr, (const f16*)nullptr, lds_xh[0], lds_xl[0], tid);
  mlp_layer< 64, 112,  50, 100,  2048,  64, 1>(wt, biasp, W1f, linv_h, linv_l, gLDS,
      lds_xh[0], lds_xl[0], lds_xh[1], lds_xl[1], tid);
  mlp_layer<128, 112, 100, 100,  9216, 176, 2>(wt, biasp, W2f, linv_h, linv_l, gLDS,
      lds_xh[1], lds_xl[1], lds_xh[0], lds_xl[0], tid);
  mlp_layer<128, 112, 100, 100, 23552, 288, 3>(wt, biasp, W3f, linv_h, linv_l, gLDS,
      lds_xh[0], lds_xl[0], lds_xh[1], lds_xl[1], tid);
  mlp_layer<128,  64, 100,  50, 37888, 400, 4>(wt, biasp, W4f, linv_h, linv_l, gLDS,
      lds_xh[1], lds_xl[1], lds_xh[0], lds_xl[0], tid);
  mlp_layer< 64,  16,  50,  10, 46080, 464, 5>(wt, biasp, W5f, linv_h, linv_l, gLDS,
      lds_xh[0], lds_xl[0], lds_xh[1], lds_xl[1], tid);

  __syncthreads();   // gLDS (written by wave 0) visible to phase C

  // ---- phase C: tensor bases + contraction + normalize (f32, verbatim) ----
  if (tid < 64) {
    int row = blockRow + tid;
    if (row < B) {
      float G[10];
      #pragma unroll
      for (int i = 0; i < 10; ++i) G[i] = gLDS[tid*10 + i];
      float S[9], W[9];
      #pragma unroll
      for (int i = 0; i < 9; ++i) { S[i] = s[(size_t)row*9 + i]; W[i] = w[(size_t)row*9 + i]; }

      float S2[9], W2[9], SW[9], WS[9];
      mm3(S,S,S2); mm3(W,W,W2); mm3(S,W,SW); mm3(W,S,WS);
      float WS2[9], S2W[9], W2S[9], SW2[9], S2W2[9], W2S2[9];
      mm3(W,S2,WS2); mm3(S2,W,S2W); mm3(W2,S,W2S); mm3(S,W2,SW2);
      mm3(S2,W2,S2W2); mm3(W2,S2,W2S2);

      float lam1 = S2[0]+S2[4]+S2[8];
      float lam2 = W2[0]+W2[4]+W2[8];
      float tr6  = SW2[0]+SW2[4]+SW2[8];
      float tr9  = S2W2[0]+S2W2[4]+S2W2[8];

      float Q[9];
      #pragma unroll
      for (int i = 0; i < 9; ++i)
        Q[i] = G[0]*S[i] + G[1]*(SW[i]-WS[i]) + G[2]*S2[i] + G[3]*W2[i]
             + G[4]*(WS2[i]-S2W[i]) + G[5]*(W2S[i]+SW2[i]) + G[8]*(W2S2[i]+S2W2[i]);

      float TA[9], TB[9];
      mm3(WS,W2,TA);  mm3(W2,SW,TB);     // T7
      #pragma unroll
      for (int i = 0; i < 9; ++i) Q[i] += G[6]*(TA[i]-TB[i]);
      mm3(SW,S2,TA);  mm3(S2,WS,TB);     // T8
      #pragma unroll
      for (int i = 0; i < 9; ++i) Q[i] += G[7]*(TA[i]-TB[i]);
      mm3(WS2,W2,TA); mm3(W2,S2W,TB);    // T10
      #pragma unroll
      for (int i = 0; i < 9; ++i) Q[i] += G[9]*(TA[i]-TB[i]);

      float diag = G[2]*lam1*(1.f/3.f) + G[3]*lam2*(1.f/3.f)
                 + G[5]*(2.f/3.f)*tr6 + G[8]*(2.f/3.f)*tr9;
      Q[0] -= diag; Q[4] -= diag; Q[8] -= diag;

      // output 1: raw
      #pragma unroll
      for (int i = 0; i < 9; ++i) out[(size_t)9*B + (size_t)row*9 + i] = Q[i];

      // output 0: deviatoric, symmetrized, normalized
      float t3 = (Q[0]+Q[4]+Q[8]) * (1.f/3.f);
      Q[0] -= t3; Q[4] -= t3; Q[8] -= t3;
      float Qs[9];
      #pragma unroll
      for (int i = 0; i < 3; ++i)
        #pragma unroll
        for (int j = 0; j < 3; ++j) Qs[i*3+j] = 0.5f*(Q[i*3+j] + Q[j*3+i]);
      float ns = 0.f;
      #pragma unroll
      for (int i = 0; i < 9; ++i) ns += Qs[i]*Qs[i];
      float rinv = 1.f / sqrtf(ns + 1e-16f);
      #pragma unroll
      for (int i = 0; i < 9; ++i) out[(size_t)row*9 + i] = Qs[i]*rinv;
    }
  }
}

// ---------------- launcher ----------------
extern "C" void kernel_launch(void* const* d_in, const int* in_sizes, int n_in,
                              void* d_out, int out_size, void* d_ws, size_t ws_size,
                              hipStream_t stream) {
  const float* s = (const float*)d_in[0];
  const float* w = (const float*)d_in[1];
  const int B = in_sizes[0] / 9;
  char* ws = (char*)d_ws;
  f16*   wt    = (f16*)ws;
  float* biasp = (float*)(ws + 94208);   // proven R2 layout, nothing beyond 96128
  float* out   = (float*)d_out;

  k0_prep<<<dim3(186), dim3(256), 0, stream>>>(
      (const float*)d_in[2],  (const float*)d_in[3],  (const float*)d_in[4],  (const float*)d_in[5],
      (const float*)d_in[6],  (const float*)d_in[7],  (const float*)d_in[8],  (const float*)d_in[9],
      (const float*)d_in[10], (const float*)d_in[11], (const float*)d_in[12], (const float*)d_in[13],
      wt, biasp);
  k_fused<<<dim3((B + 63) / 64), dim3(256), 0, stream>>>(
      wt, biasp,
      (const float*)d_in[2], (const float*)d_in[4], (const float*)d_in[6],
      (const float*)d_in[8], (const float*)d_in[10], (const float*)d_in[12],
      s, w, out, B);
}